// Round 6
// baseline (779.401 us; speedup 1.0000x reference)
//
#include <hip/hip_runtime.h>
#include <stdint.h>

// ---------------------------------------------------------------------------
// XlaQuantizedLinear: out[M,N] = (x[M,K] @ w[N,K]^T) * scaler[N]
// Round 6: round-5 single-barrier 8-phase structure, MFMA shape swapped to
// 32x32x16 (2495 TF pipe vs 2176 for 16x16x32, m119). Wave tile 128x64 =
// 4 m-tiles x 2 n-tiles of 32; acc = f32x16[4][2] (same 128 regs); fragment
// regs and per-phase b128 counts identical to round 5; staging, swizzle,
// vmcnt ledger, barriers unchanged.
// A-operand: lane l -> row l&31, k-chunk (l>>5)*8 elems (ext of verified
// 16x16x32 ko=(l>>4)*8). C/D: col=lane&31, row=(reg&3)+8*(reg>>2)+4*(l>>5)
// (m74/m101 verified).
// ---------------------------------------------------------------------------

typedef __attribute__((ext_vector_type(8))) short short8v;   // 8 bf16
typedef __attribute__((ext_vector_type(4))) short short4v;
typedef __attribute__((ext_vector_type(4))) float f32x4;
typedef __attribute__((ext_vector_type(16))) float f32x16;   // 32x32 acc

#define NXCD 8

__device__ __forceinline__ short bf16_bits(float f) {
  uint32_t u = __builtin_bit_cast(uint32_t, f);
  uint32_t r = (u + 0x7FFFu + ((u >> 16) & 1u)) >> 16;
  return (short)r;
}

__device__ __forceinline__ void gl_lds16(const void* g, void* l) {
  __builtin_amdgcn_global_load_lds(
      (const __attribute__((address_space(1))) void*)g,
      (__attribute__((address_space(3))) void*)l, 16, 0, 0);
}

// LDS map (128KB): A(buf) at buf*65536 (32KB: [256 rows][128B]),
//                  B(buf) at 32768+buf*65536.
// A lds_row = mh*128 + wr*64 + r ; B lds_row = nh*128 + wc*32 + r
// swizzle: physical kbyte = logical kbyte ^ ((lds_row&7)<<4)  (involution)
// Phase/stage/vmcnt schedule identical to round 5 (see its ledger):
//  P1 rd 0.Ah0,0.Bh0 | st 1.Bh1(t+1)          P5 rd 1.Ah0,1.Bh0 | st 0.Ah1(t+2)
//  P2 rd 0.Bh1       | st 1.Ah1(t+1)          P6 rd 1.Bh1       | st 0.Bh1(t+2)
//  P3 rd 0.Ah1       | st 0.Ah0(t+2)          P7 rd 1.Ah1       | st 1.Ah0(t+3)
//  P4 --  vmcnt(2)   | st 0.Bh0(t+2)          P8 --  vmcnt(2)   | st 1.Bh0(t+3)

__global__ __launch_bounds__(512, 2) void gemm256(
    const short* __restrict__ A, const short* __restrict__ B,
    const float* __restrict__ scaler, float* __restrict__ C,
    int M, int N, int K) {
  __shared__ alignas(16) char sm[131072];

  const int tid = threadIdx.x;
  const int l = tid & 63;
  const int w = tid >> 6;
  const int wr = w >> 2, wc = w & 3;
  const int l31 = l & 31;

  // bijective XCD-aware swizzle (m204)
  const int nwg = gridDim.x;
  const int ntn = N >> 8;
  int bid = blockIdx.x;
  int q = nwg / NXCD, rr = nwg % NXCD;
  int xcd = bid % NXCD, idx = bid / NXCD;
  int swzb = (xcd < rr ? xcd * (q + 1) : rr * (q + 1) + (xcd - rr) * q) + idx;
  const int m0 = (swzb / ntn) << 8, n0 = (swzb % ntn) << 8;

  const size_t ldkb = (size_t)K * 2;

  // --- staging per-thread bases (source pre-swizzled: rule 21) ---
  const int srow8 = l >> 3;
  const int sswz = ((l & 7) ^ srow8) << 4;
  const char* Ag = (const char*)A + (size_t)(m0 + w * 8 + srow8) * ldkb + sswz;
  const char* Bg = (const char*)B +
      (size_t)(n0 + (w >> 2) * 64 + (w & 3) * 8 + srow8) * ldkb + sswz;

  // --- read-side swizzled k offsets: phys = ((ks<<5)|kb) ^ swz ---
  const int swz = (l & 7) << 4;     // row&7 == l&7 for all frag reads
  const int kb = (l >> 5) << 4;     // 0 or 16: which 16B half of K=16 chunk

  f32x16 acc[4][2] = {};            // [m-tile 0..3][n-tile 0..1] = 128 regs
  short8v a[8], b0[4], b1[4];       // same footprint as round 5

  const int NT = K >> 6;            // K-tiles (even, >=2)

#define LDA8(buf, mh, dst) do {                                               \
    const char* _b = sm + (buf) * 65536 + ((mh)*128 + wr*64 + l31) * 128;     \
    _Pragma("unroll") for (int f = 0; f < 2; ++f)                             \
    _Pragma("unroll") for (int ks = 0; ks < 4; ++ks)                          \
      dst[f*4+ks] = *(const short8v*)(_b + f*4096 + ((((ks)<<5)|kb)^swz));    \
  } while (0)

#define LDB4(buf, nh, dst) do {                                               \
    const char* _b = sm + 32768 + (buf)*65536 + ((nh)*128 + wc*32 + l31)*128; \
    _Pragma("unroll") for (int ks = 0; ks < 4; ++ks)                          \
      dst[ks] = *(const short8v*)(_b + ((((ks)<<5)|kb)^swz));                 \
  } while (0)

#define STAGEA(buf, mh, tb) do {                                              \
    gl_lds16(Ag + (size_t)((mh)*64) * ldkb + (tb),                            \
             sm + (buf)*65536 + (mh)*16384 + w*1024);                         \
    gl_lds16(Ag + (size_t)((mh)*64 + 128) * ldkb + (tb),                      \
             sm + (buf)*65536 + (mh)*16384 + 8192 + w*1024); } while (0)

#define STAGEB(buf, nh, tb) do {                                              \
    gl_lds16(Bg + (size_t)((nh)*32) * ldkb + (tb),                            \
             sm + 32768 + (buf)*65536 + (nh)*16384 + w*1024);                 \
    gl_lds16(Bg + (size_t)((nh)*32 + 128) * ldkb + (tb),                      \
             sm + 32768 + (buf)*65536 + (nh)*16384 + 8192 + w*1024); } while (0)

#define MMAQ(mh, nh, av, bv) do {                                             \
    __builtin_amdgcn_s_setprio(1);                                            \
    _Pragma("unroll") for (int f = 0; f < 2; ++f)                             \
    _Pragma("unroll") for (int ks = 0; ks < 4; ++ks)                          \
      acc[(mh)*2+f][(nh)] = __builtin_amdgcn_mfma_f32_32x32x16_bf16(          \
          av[f*4+ks], bv[ks], acc[(mh)*2+f][(nh)], 0, 0, 0);                  \
    __builtin_amdgcn_s_setprio(0); } while (0)

#define BAR() do { __builtin_amdgcn_sched_barrier(0);                         \
    asm volatile("s_barrier" ::: "memory");                                   \
    __builtin_amdgcn_sched_barrier(0); } while (0)

#define VMW(n) asm volatile("s_waitcnt vmcnt(" #n ")" ::: "memory")

  // prologue: tile0 (4 regions) + tile1.{Ah0,Bh0}; wait tile0; publish
  STAGEA(0, 0, 0); STAGEB(0, 0, 0); STAGEA(0, 1, 0); STAGEB(0, 1, 0);
  {
    const size_t tbp = 128;  // tile 1 byte offset
    STAGEA(1, 0, tbp); STAGEB(1, 0, tbp);
  }
  VMW(4);
  BAR();

  for (int t = 0; t < NT; t += 2) {
    const bool nx = (t + 2) < NT;
    const size_t tb1 = (size_t)(t + 1) << 7;
    const size_t tb2 = (size_t)(t + 2) << 7;
    const size_t tb3 = (size_t)(t + 3) << 7;
    // P1
    LDA8(0, 0, a); LDB4(0, 0, b0);
    STAGEB(1, 1, tb1);
    BAR();
    MMAQ(0, 0, a, b0);
    // P2
    LDB4(0, 1, b1);
    STAGEA(1, 1, tb1);
    BAR();
    MMAQ(0, 1, a, b1);
    // P3
    LDA8(0, 1, a);
    if (nx) STAGEA(0, 0, tb2);
    BAR();
    MMAQ(1, 0, a, b0);
    // P4
    if (nx) { VMW(2); STAGEB(0, 0, tb2); } else { VMW(0); }
    BAR();
    MMAQ(1, 1, a, b1);
    // P5
    LDA8(1, 0, a); LDB4(1, 0, b0);
    if (nx) STAGEA(0, 1, tb2);
    BAR();
    MMAQ(0, 0, a, b0);
    // P6
    LDB4(1, 1, b1);
    if (nx) STAGEB(0, 1, tb2);
    BAR();
    MMAQ(0, 1, a, b1);
    // P7
    LDA8(1, 1, a);
    if (nx) STAGEA(1, 0, tb3);
    BAR();
    MMAQ(1, 0, a, b0);
    // P8
    if (nx) { VMW(2); STAGEB(1, 0, tb3); } else { VMW(0); }
    BAR();
    MMAQ(1, 1, a, b1);
  }

  // epilogue: per tile (mt,nt): col = n0+wc*64+nt*32+(l&31),
  // row = m0+wr*128+mt*32 + (reg&3) + 8*(reg>>2) + 4*(l>>5)
  float scl[2];
#pragma unroll
  for (int nt = 0; nt < 2; ++nt)
    scl[nt] = scaler[n0 + wc * 64 + nt * 32 + l31];
  const int colbase = n0 + wc * 64 + l31;
#pragma unroll
  for (int mt = 0; mt < 4; ++mt) {
    const int rb = m0 + wr * 128 + mt * 32 + ((l >> 5) << 2);
#pragma unroll
    for (int rg = 0; rg < 4; ++rg)
#pragma unroll
      for (int rj = 0; rj < 4; ++rj) {
        const int reg = rg * 4 + rj;
        float* cp = C + (size_t)(rb + rg * 8 + rj) * N + colbase;
        cp[0]  = acc[mt][0][reg] * scl[0];
        cp[32] = acc[mt][1][reg] * scl[1];
      }
  }
#undef LDA8
#undef LDB4
#undef STAGEA
#undef STAGEB
#undef MMAQ
#undef BAR
#undef VMW
}

// ---------------- fallback (no workspace needed) ----------------------------
#define FBM 128
#define FBN 128
#define FBK 32

__global__ __launch_bounds__(256) void gemm_fb(
    const float* __restrict__ A, const int* __restrict__ B,
    const float* __restrict__ scaler, float* __restrict__ C,
    int M, int N, int K) {
  __shared__ alignas(16) short As[FBM * FBK];
  __shared__ alignas(16) short Bs[FBN * FBK];

  const int tid = threadIdx.x;
  const int lane = tid & 63;
  const int wid = tid >> 6;
  const int wr = wid >> 1, wc = wid & 1;

  const int nwg = gridDim.x;
  const int ntn = N / FBN;
  int bid = blockIdx.x;
  int q = nwg / NXCD, r = nwg % NXCD;
  int xcd = bid % NXCD, idx = bid / NXCD;
  int swz = (xcd < r ? xcd * (q + 1) : r * (q + 1) + (xcd - r) * q) + idx;
  const int mt = swz / ntn, nt = swz % ntn;
  const int m0 = mt * FBM, n0 = nt * FBN;

  f32x4 acc[4][4] = {};
  const int kiters = K / FBK;

  for (int kt = 0; kt < kiters; ++kt) {
    const int k0 = kt * FBK;
    __syncthreads();
#pragma unroll
    for (int qq = 0; qq < 4; ++qq) {
      int chunk = qq * 256 + tid;
      int row = chunk >> 3;
      int c4 = (chunk & 7) * 4;
      float4 va = *(const float4*)&A[(size_t)(m0 + row) * K + k0 + c4];
      int4 vb = *(const int4*)&B[(size_t)(n0 + row) * K + k0 + c4];
      short4v wa, wb;
      wa[0] = bf16_bits(va.x); wa[1] = bf16_bits(va.y);
      wa[2] = bf16_bits(va.z); wa[3] = bf16_bits(va.w);
      wb[0] = bf16_bits((float)vb.x); wb[1] = bf16_bits((float)vb.y);
      wb[2] = bf16_bits((float)vb.z); wb[3] = bf16_bits((float)vb.w);
      *(short4v*)&As[row * FBK + c4] = wa;
      *(short4v*)&Bs[row * FBK + c4] = wb;
    }
    __syncthreads();
    const int ar = wr * 64 + (lane & 15);
    const int br = wc * 64 + (lane & 15);
    const int ko = (lane >> 4) * 8;
    short8v av[4], bv[4];
#pragma unroll
    for (int i = 0; i < 4; ++i) {
      av[i] = *(const short8v*)&As[(ar + i * 16) * FBK + ko];
      bv[i] = *(const short8v*)&Bs[(br + i * 16) * FBK + ko];
    }
#pragma unroll
    for (int mi = 0; mi < 4; ++mi)
#pragma unroll
      for (int ni = 0; ni < 4; ++ni)
        acc[mi][ni] = __builtin_amdgcn_mfma_f32_16x16x32_bf16(
            av[mi], bv[ni], acc[mi][ni], 0, 0, 0);
  }

  float sc[4];
  const int cc0 = n0 + wc * 64 + (lane & 15);
#pragma unroll
  for (int ni = 0; ni < 4; ++ni) sc[ni] = scaler[cc0 + ni * 16];
  const int cr0 = m0 + wr * 64 + ((lane >> 4) << 2);
#pragma unroll
  for (int mi = 0; mi < 4; ++mi)
#pragma unroll
    for (int j = 0; j < 4; ++j) {
      float* crow = C + (size_t)(cr0 + mi * 16 + j) * N;
#pragma unroll
      for (int ni = 0; ni < 4; ++ni)
        crow[cc0 + ni * 16] = acc[mi][ni][j] * sc[ni];
    }
}

// ---- conversion pre-passes (vectorized, grid-stride) -----------------------
__global__ void cvt_f32_bf16(const float* __restrict__ in,
                             short* __restrict__ out, long long n8) {
  long long i = (long long)blockIdx.x * blockDim.x + threadIdx.x;
  const long long stride = (long long)gridDim.x * blockDim.x;
  for (; i < n8; i += stride) {
    const float4* p = (const float4*)(in + i * 8);
    float4 va = p[0], vb = p[1];
    short8v o;
    o[0] = bf16_bits(va.x); o[1] = bf16_bits(va.y);
    o[2] = bf16_bits(va.z); o[3] = bf16_bits(va.w);
    o[4] = bf16_bits(vb.x); o[5] = bf16_bits(vb.y);
    o[6] = bf16_bits(vb.z); o[7] = bf16_bits(vb.w);
    *(short8v*)(out + i * 8) = o;
  }
}

__global__ void cvt_i32_bf16(const int* __restrict__ in,
                             short* __restrict__ out, long long n8) {
  long long i = (long long)blockIdx.x * blockDim.x + threadIdx.x;
  const long long stride = (long long)gridDim.x * blockDim.x;
  for (; i < n8; i += stride) {
    const int4* p = (const int4*)(in + i * 8);
    int4 va = p[0], vb = p[1];
    short8v o;
    o[0] = bf16_bits((float)va.x); o[1] = bf16_bits((float)va.y);
    o[2] = bf16_bits((float)va.z); o[3] = bf16_bits((float)va.w);
    o[4] = bf16_bits((float)vb.x); o[5] = bf16_bits((float)vb.y);
    o[6] = bf16_bits((float)vb.z); o[7] = bf16_bits((float)vb.w);
    *(short8v*)(out + i * 8) = o;
  }
}

extern "C" void kernel_launch(void* const* d_in, const int* in_sizes, int n_in,
                              void* d_out, int out_size, void* d_ws,
                              size_t ws_size, hipStream_t stream) {
  const float* x = (const float*)d_in[0];       // [M][K] fp32
  const int* w = (const int*)d_in[1];           // [N][K] int32 (int8 range)
  const float* sc = (const float*)d_in[2];      // [N] fp32
  float* out = (float*)d_out;                   // [M][N] fp32

  const long long xn = in_sizes[0];             // M*K
  const long long wn = in_sizes[1];             // N*K
  const int N = in_sizes[2];
  const int K = (int)(wn / N);
  const int M = (int)(xn / K);

  const size_t need = (size_t)(xn + wn) * sizeof(short);
  const bool ok256 = (M % 256 == 0) && (N % 256 == 0) && (K % 128 == 0);

  if (ws_size >= need && ok256) {
    short* xb = (short*)d_ws;                   // bf16 x
    short* wb = xb + xn;                        // bf16 w
    cvt_f32_bf16<<<2048, 256, 0, stream>>>(x, xb, xn / 8);
    cvt_i32_bf16<<<2048, 256, 0, stream>>>(w, wb, wn / 8);
    const int grid = (M / 256) * (N / 256);
    gemm256<<<grid, 512, 0, stream>>>(xb, wb, sc, out, M, N, K);
  } else {
    const int grid = (M / FBM) * (N / FBN);
    gemm_fb<<<grid, 256, 0, stream>>>(x, w, sc, out, M, N, K);
  }
}

// Round 7
// 715.643 us; speedup vs baseline: 1.0891x; 1.0891x over previous
//
#include <hip/hip_runtime.h>
#include <stdint.h>

// ---------------------------------------------------------------------------
// XlaQuantizedLinear: out[M,N] = (x[M,K] @ w[N,K]^T) * scaler[N]
// Round 7: round-5 structure (256x256, BK=64, single barrier/phase, counted
// vmcnt(2)@P4/P8, XOR-swizzled LDS, 16x16x32 MFMA) with ONE change:
// MMAQ's s_setprio bracket removed. setprio is a side-effecting intrinsic
// that fences instruction scheduling -> it pinned the next phase's ds_reads
// OUTSIDE the MFMA cluster. Without it the compiler may interleave
// reads(p+1) into MMAQ(p) (register deps only; sched_barrier still pins the
// s_barrier boundaries), hiding LDS latency/service under MFMA — the same
// mechanism round 4 attempted manually (which spilled), at zero reg cost.
// Also: B-frag reads issued before A in P1/P5 (first MFMA waits fewer
// outstanding lgkm ops), and the two convert pre-passes merged into one.
// Schedule ledger identical to round 5 (see table below).
//
//  phase | reads (front)        | stage (front)     | vmcnt@front
//  P1    | 0.Bh0->b0, 0.Ah0->a  | 1.Bh1 (t+1)       |
//  P2    | 0.Bh1->b1            | 1.Ah1 (t+1)       |
//  P3    | 0.Ah1->a             | 0.Ah0 (t+2)       |
//  P4    | --                   | 0.Bh0 (t+2)       | vmcnt(2) [nx] else 0
//  P5    | 1.Bh0->b0, 1.Ah0->a  | 0.Ah1 (t+2)       |
//  P6    | 1.Bh1->b1            | 0.Bh1 (t+2)       |
//  P7    | 1.Ah1->a             | 1.Ah0 (t+3)       |
//  P8    | --                   | 1.Bh0 (t+3)       | vmcnt(2) [nx] else 0
// ---------------------------------------------------------------------------

typedef __attribute__((ext_vector_type(8))) short short8v;  // 8 bf16
typedef __attribute__((ext_vector_type(4))) short short4v;
typedef __attribute__((ext_vector_type(4))) float f32x4;

#define NXCD 8

__device__ __forceinline__ short bf16_bits(float f) {
  uint32_t u = __builtin_bit_cast(uint32_t, f);
  uint32_t r = (u + 0x7FFFu + ((u >> 16) & 1u)) >> 16;
  return (short)r;
}

__device__ __forceinline__ void gl_lds16(const void* g, void* l) {
  __builtin_amdgcn_global_load_lds(
      (const __attribute__((address_space(1))) void*)g,
      (__attribute__((address_space(3))) void*)l, 16, 0, 0);
}

// LDS map (128KB): A(buf) at buf*65536 (32KB: [256 rows][128B]),
//                  B(buf) at 32768+buf*65536.
// A lds_row = mh*128 + wr*64 + r ; B lds_row = nh*128 + wc*32 + r
// swizzle: physical kbyte = logical kbyte ^ ((lds_row&7)<<4)  (involution)

__global__ __launch_bounds__(512, 2) void gemm256(
    const short* __restrict__ A, const short* __restrict__ B,
    const float* __restrict__ scaler, float* __restrict__ C,
    int M, int N, int K) {
  __shared__ alignas(16) char sm[131072];

  const int tid = threadIdx.x;
  const int l = tid & 63;
  const int w = tid >> 6;
  const int wr = w >> 2, wc = w & 3;
  const int ln15 = l & 15;

  // bijective XCD-aware swizzle (m204)
  const int nwg = gridDim.x;
  const int ntn = N >> 8;
  int bid = blockIdx.x;
  int q = nwg / NXCD, rr = nwg % NXCD;
  int xcd = bid % NXCD, idx = bid / NXCD;
  int swz = (xcd < rr ? xcd * (q + 1) : rr * (q + 1) + (xcd - rr) * q) + idx;
  const int m0 = (swz / ntn) << 8, n0 = (swz % ntn) << 8;

  const size_t ldkb = (size_t)K * 2;

  // --- staging per-thread bases (source pre-swizzled: rule 21) ---
  const int srow8 = l >> 3;
  const int sswz = ((l & 7) ^ srow8) << 4;
  const char* Ag = (const char*)A + (size_t)(m0 + w * 8 + srow8) * ldkb + sswz;
  const char* Bg = (const char*)B +
      (size_t)(n0 + (w >> 2) * 64 + (w & 3) * 8 + srow8) * ldkb + sswz;

  // --- read-side swizzled k offsets ---
  const int swzc = (l & 7) << 4;
  const int klo = (l >> 4) << 4;
  const int e45 = klo ^ (swzc & 48);
  const int s6 = swzc & 64;
  const int kof0 = e45 | s6;
  const int kof1 = e45 | (64 ^ s6);

  f32x4 acc[8][4] = {};                            // 128 acc regs
  short8v a[8], b0[4], b1[4];                      // 64 frag regs

  const int NT = K >> 6;                           // K-tiles (even, >=2)

#define LDA8(buf, mh, dst) do {                                               \
    const char* _b = sm + (buf) * 65536 + ((mh)*128 + wr*64 + ln15) * 128;    \
    _Pragma("unroll") for (int f = 0; f < 4; ++f) {                           \
      dst[f*2+0] = *(const short8v*)(_b + f*2048 + kof0);                     \
      dst[f*2+1] = *(const short8v*)(_b + f*2048 + kof1); } } while (0)

#define LDB4(buf, nh, dst) do {                                               \
    const char* _b = sm + 32768 + (buf)*65536 + ((nh)*128 + wc*32 + ln15)*128;\
    _Pragma("unroll") for (int nf = 0; nf < 2; ++nf) {                        \
      dst[nf*2+0] = *(const short8v*)(_b + nf*2048 + kof0);                   \
      dst[nf*2+1] = *(const short8v*)(_b + nf*2048 + kof1); } } while (0)

#define STAGEA(buf, mh, tb) do {                                              \
    gl_lds16(Ag + (size_t)((mh)*64) * ldkb + (tb),                            \
             sm + (buf)*65536 + (mh)*16384 + w*1024);                         \
    gl_lds16(Ag + (size_t)((mh)*64 + 128) * ldkb + (tb),                      \
             sm + (buf)*65536 + (mh)*16384 + 8192 + w*1024); } while (0)

#define STAGEB(buf, nh, tb) do {                                              \
    gl_lds16(Bg + (size_t)((nh)*32) * ldkb + (tb),                            \
             sm + 32768 + (buf)*65536 + (nh)*16384 + w*1024);                 \
    gl_lds16(Bg + (size_t)((nh)*32 + 128) * ldkb + (tb),                      \
             sm + 32768 + (buf)*65536 + (nh)*16384 + 8192 + w*1024); } while (0)

// no setprio: keep the MFMA cluster free of scheduling fences so the
// compiler can interleave the next phase's ds_reads into it.
#define MMAQ(mh, nh, av, bv) do {                                             \
    _Pragma("unroll") for (int f = 0; f < 4; ++f)                             \
    _Pragma("unroll") for (int nf = 0; nf < 2; ++nf)                          \
    _Pragma("unroll") for (int ks = 0; ks < 2; ++ks)                          \
      acc[(mh)*4+f][(nh)*2+nf] = __builtin_amdgcn_mfma_f32_16x16x32_bf16(     \
          av[f*2+ks], bv[nf*2+ks], acc[(mh)*4+f][(nh)*2+nf], 0, 0, 0);        \
  } while (0)

#define BAR() do { __builtin_amdgcn_sched_barrier(0);                         \
    asm volatile("s_barrier" ::: "memory");                                   \
    __builtin_amdgcn_sched_barrier(0); } while (0)

#define VMW(n) asm volatile("s_waitcnt vmcnt(" #n ")" ::: "memory")

  // prologue: tile0 (4 regions) + tile1.{Ah0,Bh0}; wait tile0; publish
  STAGEA(0, 0, 0); STAGEB(0, 0, 0); STAGEA(0, 1, 0); STAGEB(0, 1, 0);
  {
    const size_t tbp = 128;  // tile 1 byte offset
    STAGEA(1, 0, tbp); STAGEB(1, 0, tbp);
  }
  VMW(4);
  BAR();

  for (int t = 0; t < NT; t += 2) {
    const bool nx = (t + 2) < NT;
    const size_t tb1 = (size_t)(t + 1) << 7;
    const size_t tb2 = (size_t)(t + 2) << 7;
    const size_t tb3 = (size_t)(t + 3) << 7;
    // P1
    LDB4(0, 0, b0); LDA8(0, 0, a);
    STAGEB(1, 1, tb1);
    BAR();
    MMAQ(0, 0, a, b0);
    // P2
    LDB4(0, 1, b1);
    STAGEA(1, 1, tb1);
    BAR();
    MMAQ(0, 1, a, b1);
    // P3
    LDA8(0, 1, a);
    if (nx) STAGEA(0, 0, tb2);
    BAR();
    MMAQ(1, 0, a, b0);
    // P4
    if (nx) { VMW(2); STAGEB(0, 0, tb2); } else { VMW(0); }
    BAR();
    MMAQ(1, 1, a, b1);
    // P5
    LDB4(1, 0, b0); LDA8(1, 0, a);
    if (nx) STAGEA(0, 1, tb2);
    BAR();
    MMAQ(0, 0, a, b0);
    // P6
    LDB4(1, 1, b1);
    if (nx) STAGEB(0, 1, tb2);
    BAR();
    MMAQ(0, 1, a, b1);
    // P7
    LDA8(1, 1, a);
    if (nx) STAGEA(1, 0, tb3);
    BAR();
    MMAQ(1, 0, a, b0);
    // P8
    if (nx) { VMW(2); STAGEB(1, 0, tb3); } else { VMW(0); }
    BAR();
    MMAQ(1, 1, a, b1);
  }

  // epilogue: C row = m0+wr*128+mh*64+f*16+(l>>4)*4+j; col = n0+wc*64+nh*32+nf*16+ln15
  float scl[4];
#pragma unroll
  for (int ng = 0; ng < 4; ++ng)
    scl[ng] = scaler[n0 + wc * 64 + (ng >> 1) * 32 + (ng & 1) * 16 + ln15];
  const int row0 = m0 + wr * 128 + ((l >> 4) << 2);
  const int col0 = n0 + wc * 64 + ln15;
#pragma unroll
  for (int mf = 0; mf < 8; ++mf) {
    const int rbase = row0 + (mf >> 2) * 64 + (mf & 3) * 16;
#pragma unroll
    for (int j = 0; j < 4; ++j) {
      float* cp = C + (size_t)(rbase + j) * N + col0;
#pragma unroll
      for (int ng = 0; ng < 4; ++ng)
        cp[(ng >> 1) * 32 + (ng & 1) * 16] = acc[mf][ng][j] * scl[ng];
    }
  }
#undef LDA8
#undef LDB4
#undef STAGEA
#undef STAGEB
#undef MMAQ
#undef BAR
#undef VMW
}

// ---------------- fallback (no workspace needed) ----------------------------
#define FBM 128
#define FBN 128
#define FBK 32

__global__ __launch_bounds__(256) void gemm_fb(
    const float* __restrict__ A, const int* __restrict__ B,
    const float* __restrict__ scaler, float* __restrict__ C,
    int M, int N, int K) {
  __shared__ alignas(16) short As[FBM * FBK];
  __shared__ alignas(16) short Bs[FBN * FBK];

  const int tid = threadIdx.x;
  const int lane = tid & 63;
  const int wid = tid >> 6;
  const int wr = wid >> 1, wc = wid & 1;

  const int nwg = gridDim.x;
  const int ntn = N / FBN;
  int bid = blockIdx.x;
  int q = nwg / NXCD, r = nwg % NXCD;
  int xcd = bid % NXCD, idx = bid / NXCD;
  int swz = (xcd < r ? xcd * (q + 1) : r * (q + 1) + (xcd - r) * q) + idx;
  const int mt = swz / ntn, nt = swz % ntn;
  const int m0 = mt * FBM, n0 = nt * FBN;

  f32x4 acc[4][4] = {};
  const int kiters = K / FBK;

  for (int kt = 0; kt < kiters; ++kt) {
    const int k0 = kt * FBK;
    __syncthreads();
#pragma unroll
    for (int qq = 0; qq < 4; ++qq) {
      int chunk = qq * 256 + tid;
      int row = chunk >> 3;
      int c4 = (chunk & 7) * 4;
      float4 va = *(const float4*)&A[(size_t)(m0 + row) * K + k0 + c4];
      int4 vb = *(const int4*)&B[(size_t)(n0 + row) * K + k0 + c4];
      short4v wa, wb;
      wa[0] = bf16_bits(va.x); wa[1] = bf16_bits(va.y);
      wa[2] = bf16_bits(va.z); wa[3] = bf16_bits(va.w);
      wb[0] = bf16_bits((float)vb.x); wb[1] = bf16_bits((float)vb.y);
      wb[2] = bf16_bits((float)vb.z); wb[3] = bf16_bits((float)vb.w);
      *(short4v*)&As[row * FBK + c4] = wa;
      *(short4v*)&Bs[row * FBK + c4] = wb;
    }
    __syncthreads();
    const int ar = wr * 64 + (lane & 15);
    const int br = wc * 64 + (lane & 15);
    const int ko = (lane >> 4) * 8;
    short8v av[4], bv[4];
#pragma unroll
    for (int i = 0; i < 4; ++i) {
      av[i] = *(const short8v*)&As[(ar + i * 16) * FBK + ko];
      bv[i] = *(const short8v*)&Bs[(br + i * 16) * FBK + ko];
    }
#pragma unroll
    for (int mi = 0; mi < 4; ++mi)
#pragma unroll
      for (int ni = 0; ni < 4; ++ni)
        acc[mi][ni] = __builtin_amdgcn_mfma_f32_16x16x32_bf16(
            av[mi], bv[ni], acc[mi][ni], 0, 0, 0);
  }

  float sc[4];
  const int cc0 = n0 + wc * 64 + (lane & 15);
#pragma unroll
  for (int ni = 0; ni < 4; ++ni) sc[ni] = scaler[cc0 + ni * 16];
  const int cr0 = m0 + wr * 64 + ((lane >> 4) << 2);
#pragma unroll
  for (int mi = 0; mi < 4; ++mi)
#pragma unroll
    for (int j = 0; j < 4; ++j) {
      float* crow = C + (size_t)(cr0 + mi * 16 + j) * N;
#pragma unroll
      for (int ni = 0; ni < 4; ++ni)
        crow[cc0 + ni * 16] = acc[mi][ni][j] * sc[ni];
    }
}

// ---- merged conversion pre-pass (one launch): x fp32->bf16, w int32->bf16 --
__global__ void cvt_all(const float* __restrict__ x, const int* __restrict__ wq,
                        short* __restrict__ xb, short* __restrict__ wb,
                        long long nx8, long long nw8) {
  long long i = (long long)blockIdx.x * blockDim.x + threadIdx.x;
  const long long stride = (long long)gridDim.x * blockDim.x;
  const long long ntot = nx8 + nw8;
  for (; i < ntot; i += stride) {
    if (i < nx8) {
      const float4* p = (const float4*)(x + i * 8);
      float4 va = p[0], vb = p[1];
      short8v o;
      o[0] = bf16_bits(va.x); o[1] = bf16_bits(va.y);
      o[2] = bf16_bits(va.z); o[3] = bf16_bits(va.w);
      o[4] = bf16_bits(vb.x); o[5] = bf16_bits(vb.y);
      o[6] = bf16_bits(vb.z); o[7] = bf16_bits(vb.w);
      *(short8v*)(xb + i * 8) = o;
    } else {
      const long long j = i - nx8;
      const int4* p = (const int4*)(wq + j * 8);
      int4 va = p[0], vb = p[1];
      short8v o;
      o[0] = bf16_bits((float)va.x); o[1] = bf16_bits((float)va.y);
      o[2] = bf16_bits((float)va.z); o[3] = bf16_bits((float)va.w);
      o[4] = bf16_bits((float)vb.x); o[5] = bf16_bits((float)vb.y);
      o[6] = bf16_bits((float)vb.z); o[7] = bf16_bits((float)vb.w);
      *(short8v*)(wb + j * 8) = o;
    }
  }
}

extern "C" void kernel_launch(void* const* d_in, const int* in_sizes, int n_in,
                              void* d_out, int out_size, void* d_ws,
                              size_t ws_size, hipStream_t stream) {
  const float* x = (const float*)d_in[0];       // [M][K] fp32
  const int* w = (const int*)d_in[1];           // [N][K] int32 (int8 range)
  const float* sc = (const float*)d_in[2];      // [N] fp32
  float* out = (float*)d_out;                   // [M][N] fp32

  const long long xn = in_sizes[0];             // M*K
  const long long wn = in_sizes[1];             // N*K
  const int N = in_sizes[2];
  const int K = (int)(wn / N);
  const int M = (int)(xn / K);

  const size_t need = (size_t)(xn + wn) * sizeof(short);
  const bool ok256 = (M % 256 == 0) && (N % 256 == 0) && (K % 128 == 0);

  if (ws_size >= need && ok256) {
    short* xb = (short*)d_ws;                   // bf16 x
    short* wb = xb + xn;                        // bf16 w
    cvt_all<<<2048, 256, 0, stream>>>(x, w, xb, wb, xn / 8, wn / 8);
    const int grid = (M / 256) * (N / 256);
    gemm256<<<grid, 512, 0, stream>>>(xb, wb, sc, out, M, N, K);
  } else {
    const int grid = (M / FBM) * (N / FBN);
    gemm_fb<<<grid, 256, 0, stream>>>(x, w, sc, out, M, N, K);
  }
}

// Round 8
// 705.910 us; speedup vs baseline: 1.1041x; 1.0138x over previous
//
#include <hip/hip_runtime.h>
#include <stdint.h>

// ---------------------------------------------------------------------------
// XlaQuantizedLinear: out[M,N] = (x[M,K] @ w[N,K]^T) * scaler[N]
// Round 8: 256x256 tile, 5-region LDS RING (80 KB -> 2 blocks/CU), 4 phases
// per K-tile. Each 16 KB region is ds_read exactly once per tile (fragments
// persist in regs across the two quadrant-phases that consume them), so a
// 5-deep ring replaces the 2x64KB double buffer. Cross-BLOCK overlap (2
// blocks/CU) now hides barrier+LDS stalls instead of intra-block pipelining.
//
// Slots: s = 4t+j, j: 0=A0,1=B0,2=B1,3=A1. Region(s) = (s mod 5)*16KB.
// Phase p = 4t+j (j=1..4):
//  φ1: VMW(4); BAR; MMAQ(1,1)(t-1); read A0(t)->a, B0(t)->b0; stage A0(t+1)
//  φ2: VMW(4); BAR; MMAQ(0,0)(t);   read B1(t)->b1;           stage B0(t+1)
//  φ3: VMW(4); BAR; MMAQ(0,1)(t);   read A1(t)->a;            stage B1(t+1)
//  φ4:         BAR; MMAQ(1,0)(t);                              stage A1(t+1)
// Ledger: stage(s)@phase s-3 (2 gl_lds); read(s)@s (j=1,2,3) or s+1 (j=0).
//  - vmcnt: entering φ1(t): outstanding = slots 4t..4t+3 (8 loads);
//    VMW(4) retires A0,B0(t) (read this phase). φ2: retires B1. φ3: A1.
//  - WAR: stage(s) writes region of slot s-5, whose read phase is <= s-4;
//    stage phase s-3 >= read+1 with a barrier between (reads are issued
//    before BAR(s-3); stage after). Lead 3-4 phases covers HBM latency.
//  - reg liveness: b0 read φ1 used φ2,φ4; b1 read φ2 used φ3,φ1(t+1);
//    a holds A0 (φ1..φ3) then A1 (φ3..φ1(t+1)); MFMA-before-read in-phase
//    ordering makes the single a-bank safe (in-order issue reads operands
//    at MFMA issue before the ds_read overwrites them).
// Peels: t=0 (no MMAQ(1,1)), t=NT-1 (no stages; VMW 4/2/0), final MMAQ(1,1).
// ---------------------------------------------------------------------------

typedef __attribute__((ext_vector_type(8))) short short8v;  // 8 bf16
typedef __attribute__((ext_vector_type(4))) short short4v;
typedef __attribute__((ext_vector_type(4))) float f32x4;

#define NXCD 8
#define RSZ 16384
#define RING 81920

__device__ __forceinline__ short bf16_bits(float f) {
  uint32_t u = __builtin_bit_cast(uint32_t, f);
  uint32_t r = (u + 0x7FFFu + ((u >> 16) & 1u)) >> 16;
  return (short)r;
}

__device__ __forceinline__ void gl_lds16(const void* g, void* l) {
  __builtin_amdgcn_global_load_lds(
      (const __attribute__((address_space(1))) void*)g,
      (__attribute__((address_space(3))) void*)l, 16, 0, 0);
}

// Region content (16 KB = 128 rows x 128 B), same layouts as rounds 5-7:
//  A region (half mh): region row = wr'*64+r'' <-> block A row wr'*128+mh*64+r''
//  B region (half nh): region row = wc'*32+r'  <-> block B row wc'*64+nh*32+r'
// swizzle: physical kbyte = logical kbyte ^ ((row&7)<<4)  (involution)

__global__ __launch_bounds__(512, 2) void gemm256(
    const short* __restrict__ A, const short* __restrict__ B,
    const float* __restrict__ scaler, float* __restrict__ C,
    int M, int N, int K) {
  __shared__ alignas(16) char sm[RING];  // 80 KB -> 2 blocks/CU

  const int tid = threadIdx.x;
  const int l = tid & 63;
  const int w = tid >> 6;
  const int wr = w >> 2, wc = w & 3;
  const int ln15 = l & 15;

  // bijective XCD-aware swizzle (m204)
  const int nwg = gridDim.x;
  const int ntn = N >> 8;
  int bid = blockIdx.x;
  int q = nwg / NXCD, rr = nwg % NXCD;
  int xcd = bid % NXCD, idx = bid / NXCD;
  int swz = (xcd < rr ? xcd * (q + 1) : rr * (q + 1) + (xcd - rr) * q) + idx;
  const int m0 = (swz / ntn) << 8, n0 = (swz % ntn) << 8;

  const size_t ldkb = (size_t)K * 2;

  // staging per-thread bases (source pre-swizzled: rule 21)
  const int srow8 = l >> 3;
  const int sswz = ((l & 7) ^ srow8) << 4;
  const char* Ag = (const char*)A + (size_t)(m0 + w * 8 + srow8) * ldkb + sswz;
  const char* Bg = (const char*)B +
      (size_t)(n0 + (w >> 2) * 64 + (w & 3) * 8 + srow8) * ldkb + sswz;

  // read-side swizzled k offsets
  const int swzc = (l & 7) << 4;
  const int klo = (l >> 4) << 4;
  const int e45 = klo ^ (swzc & 48);
  const int s6 = swzc & 64;
  const int kof0 = e45 | s6;
  const int kof1 = e45 | (64 ^ s6);

  f32x4 acc[8][4] = {};              // 128 acc regs
  short8v a[8], b0[4], b1[4];        // 64 frag regs

  const int NT = K >> 6;             // K-tiles (>=2)

#define WRAP(x) ((x) >= RING ? (x) - RING : (x))

#define LDA8R(base, dst) do {                                                 \
    const char* _b = sm + (base) + (wr * 64 + ln15) * 128;                    \
    _Pragma("unroll") for (int f = 0; f < 4; ++f) {                           \
      dst[f*2+0] = *(const short8v*)(_b + f*2048 + kof0);                     \
      dst[f*2+1] = *(const short8v*)(_b + f*2048 + kof1); } } while (0)

#define LDB4R(base, dst) do {                                                 \
    const char* _b = sm + (base) + (wc * 32 + ln15) * 128;                    \
    _Pragma("unroll") for (int nf = 0; nf < 2; ++nf) {                        \
      dst[nf*2+0] = *(const short8v*)(_b + nf*2048 + kof0);                   \
      dst[nf*2+1] = *(const short8v*)(_b + nf*2048 + kof1); } } while (0)

#define STAGE_A(base, mh, tb) do {                                            \
    gl_lds16(Ag + (size_t)((mh)*64) * ldkb + (tb),                            \
             sm + (base) + w * 1024);                                         \
    gl_lds16(Ag + (size_t)((mh)*64 + 128) * ldkb + (tb),                      \
             sm + (base) + 8192 + w * 1024); } while (0)

#define STAGE_B(base, nh, tb) do {                                            \
    gl_lds16(Bg + (size_t)((nh)*32) * ldkb + (tb),                            \
             sm + (base) + w * 1024);                                         \
    gl_lds16(Bg + (size_t)((nh)*32 + 128) * ldkb + (tb),                      \
             sm + (base) + 8192 + w * 1024); } while (0)

#define MMAQ(mh, nh, av, bv) do {                                             \
    _Pragma("unroll") for (int f = 0; f < 4; ++f)                             \
    _Pragma("unroll") for (int nf = 0; nf < 2; ++nf)                          \
    _Pragma("unroll") for (int ks = 0; ks < 2; ++ks)                          \
      acc[(mh)*4+f][(nh)*2+nf] = __builtin_amdgcn_mfma_f32_16x16x32_bf16(     \
          av[f*2+ks], bv[nf*2+ks], acc[(mh)*4+f][(nh)*2+nf], 0, 0, 0);        \
  } while (0)

#define BAR() do { __builtin_amdgcn_sched_barrier(0);                         \
    asm volatile("s_barrier" ::: "memory");                                   \
    __builtin_amdgcn_sched_barrier(0); } while (0)

#define VMW(n) asm volatile("s_waitcnt vmcnt(" #n ")" ::: "memory")

  // prologue: stage tile0's 4 regions (slots 0..3 -> ring regions 0..3)
  STAGE_A(0 * RSZ, 0, 0);
  STAGE_B(1 * RSZ, 0, 0);
  STAGE_B(2 * RSZ, 1, 0);
  STAGE_A(3 * RSZ, 1, 0);

  int rb = 0;  // ring base of slot 4t (uniform)

  // ---- t = 0 peel (no MMAQ(1,1) carry-in) ----
  {
    const int rA0 = rb, rB0 = WRAP(rb + RSZ), rB1 = WRAP(rb + 2 * RSZ);
    const int rA1 = WRAP(rb + 3 * RSZ), rN = WRAP(rb + 4 * RSZ);
    const size_t tbn = 128;  // tile 1 byte offset
    VMW(4); BAR();
    LDA8R(rA0, a); LDB4R(rB0, b0);
    STAGE_A(rN, 0, tbn);
    VMW(4); BAR();
    MMAQ(0, 0, a, b0);
    LDB4R(rB1, b1);
    STAGE_B(rA0, 0, tbn);
    VMW(4); BAR();
    MMAQ(0, 1, a, b1);
    LDA8R(rA1, a);
    STAGE_B(rB0, 1, tbn);
    BAR();
    MMAQ(1, 0, a, b0);
    STAGE_A(rB1, 1, tbn);
    rb = rN;
  }

  // ---- main tiles t = 1 .. NT-2 ----
  for (int t = 1; t < NT - 1; ++t) {
    const int rA0 = rb, rB0 = WRAP(rb + RSZ), rB1 = WRAP(rb + 2 * RSZ);
    const int rA1 = WRAP(rb + 3 * RSZ), rN = WRAP(rb + 4 * RSZ);
    const size_t tbn = (size_t)(t + 1) << 7;
    // φ1
    VMW(4); BAR();
    MMAQ(1, 1, a, b1);               // tile t-1 (a=A1(t-1), b1(t-1))
    LDA8R(rA0, a); LDB4R(rB0, b0);
    STAGE_A(rN, 0, tbn);
    // φ2
    VMW(4); BAR();
    MMAQ(0, 0, a, b0);
    LDB4R(rB1, b1);
    STAGE_B(rA0, 0, tbn);
    // φ3
    VMW(4); BAR();
    MMAQ(0, 1, a, b1);
    LDA8R(rA1, a);
    STAGE_B(rB0, 1, tbn);
    // φ4
    BAR();
    MMAQ(1, 0, a, b0);
    STAGE_A(rB1, 1, tbn);
    rb = rN;
  }

  // ---- last tile t = NT-1 (no stages; draining vmcnt) ----
  {
    const int rA0 = rb, rB0 = WRAP(rb + RSZ), rB1 = WRAP(rb + 2 * RSZ);
    const int rA1 = WRAP(rb + 3 * RSZ);
    VMW(4); BAR();
    MMAQ(1, 1, a, b1);
    LDA8R(rA0, a); LDB4R(rB0, b0);
    VMW(2); BAR();
    MMAQ(0, 0, a, b0);
    LDB4R(rB1, b1);
    VMW(0); BAR();
    MMAQ(0, 1, a, b1);
    LDA8R(rA1, a);
    BAR();
    MMAQ(1, 0, a, b0);
  }
  MMAQ(1, 1, a, b1);                 // final carry-out

  // epilogue: C row = m0+wr*128+mh*64+f*16+(l>>4)*4+j; col = n0+wc*64+nh*32+nf*16+ln15
  float scl[4];
#pragma unroll
  for (int ng = 0; ng < 4; ++ng)
    scl[ng] = scaler[n0 + wc * 64 + (ng >> 1) * 32 + (ng & 1) * 16 + ln15];
  const int row0 = m0 + wr * 128 + ((l >> 4) << 2);
  const int col0 = n0 + wc * 64 + ln15;
#pragma unroll
  for (int mf = 0; mf < 8; ++mf) {
    const int rbase = row0 + (mf >> 2) * 64 + (mf & 3) * 16;
#pragma unroll
    for (int j = 0; j < 4; ++j) {
      float* cp = C + (size_t)(rbase + j) * N + col0;
#pragma unroll
      for (int ng = 0; ng < 4; ++ng)
        cp[(ng >> 1) * 32 + (ng & 1) * 16] = acc[mf][ng][j] * scl[ng];
    }
  }
#undef WRAP
#undef LDA8R
#undef LDB4R
#undef STAGE_A
#undef STAGE_B
#undef MMAQ
#undef BAR
#undef VMW
}

// ---------------- fallback (no workspace needed) ----------------------------
#define FBM 128
#define FBN 128
#define FBK 32

__global__ __launch_bounds__(256) void gemm_fb(
    const float* __restrict__ A, const int* __restrict__ B,
    const float* __restrict__ scaler, float* __restrict__ C,
    int M, int N, int K) {
  __shared__ alignas(16) short As[FBM * FBK];
  __shared__ alignas(16) short Bs[FBN * FBK];

  const int tid = threadIdx.x;
  const int lane = tid & 63;
  const int wid = tid >> 6;
  const int wr = wid >> 1, wc = wid & 1;

  const int nwg = gridDim.x;
  const int ntn = N / FBN;
  int bid = blockIdx.x;
  int q = nwg / NXCD, r = nwg % NXCD;
  int xcd = bid % NXCD, idx = bid / NXCD;
  int swz = (xcd < r ? xcd * (q + 1) : r * (q + 1) + (xcd - r) * q) + idx;
  const int mt = swz / ntn, nt = swz % ntn;
  const int m0 = mt * FBM, n0 = nt * FBN;

  f32x4 acc[4][4] = {};
  const int kiters = K / FBK;

  for (int kt = 0; kt < kiters; ++kt) {
    const int k0 = kt * FBK;
    __syncthreads();
#pragma unroll
    for (int qq = 0; qq < 4; ++qq) {
      int chunk = qq * 256 + tid;
      int row = chunk >> 3;
      int c4 = (chunk & 7) * 4;
      float4 va = *(const float4*)&A[(size_t)(m0 + row) * K + k0 + c4];
      int4 vb = *(const int4*)&B[(size_t)(n0 + row) * K + k0 + c4];
      short4v wa, wb;
      wa[0] = bf16_bits(va.x); wa[1] = bf16_bits(va.y);
      wa[2] = bf16_bits(va.z); wa[3] = bf16_bits(va.w);
      wb[0] = bf16_bits((float)vb.x); wb[1] = bf16_bits((float)vb.y);
      wb[2] = bf16_bits((float)vb.z); wb[3] = bf16_bits((float)vb.w);
      *(short4v*)&As[row * FBK + c4] = wa;
      *(short4v*)&Bs[row * FBK + c4] = wb;
    }
    __syncthreads();
    const int ar = wr * 64 + (lane & 15);
    const int br = wc * 64 + (lane & 15);
    const int ko = (lane >> 4) * 8;
    short8v av[4], bv[4];
#pragma unroll
    for (int i = 0; i < 4; ++i) {
      av[i] = *(const short8v*)&As[(ar + i * 16) * FBK + ko];
      bv[i] = *(const short8v*)&Bs[(br + i * 16) * FBK + ko];
    }
#pragma unroll
    for (int mi = 0; mi < 4; ++mi)
#pragma unroll
      for (int ni = 0; ni < 4; ++ni)
        acc[mi][ni] = __builtin_amdgcn_mfma_f32_16x16x32_bf16(
            av[mi], bv[ni], acc[mi][ni], 0, 0, 0);
  }

  float sc[4];
  const int cc0 = n0 + wc * 64 + (lane & 15);
#pragma unroll
  for (int ni = 0; ni < 4; ++ni) sc[ni] = scaler[cc0 + ni * 16];
  const int cr0 = m0 + wr * 64 + ((lane >> 4) << 2);
#pragma unroll
  for (int mi = 0; mi < 4; ++mi)
#pragma unroll
    for (int j = 0; j < 4; ++j) {
      float* crow = C + (size_t)(cr0 + mi * 16 + j) * N;
#pragma unroll
      for (int ni = 0; ni < 4; ++ni)
        crow[cc0 + ni * 16] = acc[mi][ni][j] * sc[ni];
    }
}

// ---- merged conversion pre-pass (one launch): x fp32->bf16, w int32->bf16 --
__global__ void cvt_all(const float* __restrict__ x, const int* __restrict__ wq,
                        short* __restrict__ xb, short* __restrict__ wb,
                        long long nx8, long long nw8) {
  long long i = (long long)blockIdx.x * blockDim.x + threadIdx.x;
  const long long stride = (long long)gridDim.x * blockDim.x;
  const long long ntot = nx8 + nw8;
  for (; i < ntot; i += stride) {
    if (i < nx8) {
      const float4* p = (const float4*)(x + i * 8);
      float4 va = p[0], vb = p[1];
      short8v o;
      o[0] = bf16_bits(va.x); o[1] = bf16_bits(va.y);
      o[2] = bf16_bits(va.z); o[3] = bf16_bits(va.w);
      o[4] = bf16_bits(vb.x); o[5] = bf16_bits(vb.y);
      o[6] = bf16_bits(vb.z); o[7] = bf16_bits(vb.w);
      *(short8v*)(xb + i * 8) = o;
    } else {
      const long long j = i - nx8;
      const int4* p = (const int4*)(wq + j * 8);
      int4 va = p[0], vb = p[1];
      short8v o;
      o[0] = bf16_bits((float)va.x); o[1] = bf16_bits((float)va.y);
      o[2] = bf16_bits((float)va.z); o[3] = bf16_bits((float)va.w);
      o[4] = bf16_bits((float)vb.x); o[5] = bf16_bits((float)vb.y);
      o[6] = bf16_bits((float)vb.z); o[7] = bf16_bits((float)vb.w);
      *(short8v*)(wb + j * 8) = o;
    }
  }
}

extern "C" void kernel_launch(void* const* d_in, const int* in_sizes, int n_in,
                              void* d_out, int out_size, void* d_ws,
                              size_t ws_size, hipStream_t stream) {
  const float* x = (const float*)d_in[0];       // [M][K] fp32
  const int* w = (const int*)d_in[1];           // [N][K] int32 (int8 range)
  const float* sc = (const float*)d_in[2];      // [N] fp32
  float* out = (float*)d_out;                   // [M][N] fp32

  const long long xn = in_sizes[0];             // M*K
  const long long wn = in_sizes[1];             // N*K
  const int N = in_sizes[2];
  const int K = (int)(wn / N);
  const int M = (int)(xn / K);

  const size_t need = (size_t)(xn + wn) * sizeof(short);
  const bool ok256 = (M % 256 == 0) && (N % 256 == 0) && (K % 128 == 0);

  if (ws_size >= need && ok256) {
    short* xb = (short*)d_ws;                   // bf16 x
    short* wb = xb + xn;                        // bf16 w
    cvt_all<<<2048, 256, 0, stream>>>(x, w, xb, wb, xn / 8, wn / 8);
    const int grid = (M / 256) * (N / 256);
    gemm256<<<grid, 512, 0, stream>>>(xb, wb, sc, out, M, N, K);
  } else {
    const int grid = (M / FBM) * (N / FBN);
    gemm_fb<<<grid, 256, 0, stream>>>(x, w, sc, out, M, N, K);
  }
}